// Round 4
// baseline (370.310 us; speedup 1.0000x reference)
//
#include <hip/hip_runtime.h>
#include <stdint.h>

typedef unsigned short b16;
typedef unsigned int   u32;
typedef __attribute__((ext_vector_type(8))) short short8;   // 8 x bf16 (4 VGPR)
typedef __attribute__((ext_vector_type(4))) float f32x4;    // 4 x fp32 acc

#define DEVI static __device__ __forceinline__

constexpr int CCH   = 256;           // channels
constexpr int IMG   = 192;           // H = W
constexpr int PLANE = IMG * IMG;     // 36864
constexpr int WTOK  = 256;           // tokens per 16x16 window
constexpr int WELEM = WTOK * CCH;    // 65536 elements per window slab
constexpr long XN   = 18874368;      // elements per input tensor (2*256*192*192)

DEVI b16 f2bf(float f) {             // fp32 -> bf16 round-to-nearest-even
  u32 u = __float_as_uint(f);
  u += 0x7fffu + ((u >> 16) & 1u);
  return (b16)(u >> 16);
}

// async global->LDS, 16B per lane; LDS dest = wave-uniform base + lane*16
DEVI void gl2lds16(const b16* g, b16* l) {
  __builtin_amdgcn_global_load_lds(
      (const __attribute__((address_space(1))) u32*)g,
      (__attribute__((address_space(3))) u32*)l, 16, 0, 0);
}

DEVI short8 lds8(const b16* p) { return *reinterpret_cast<const short8*>(p); }

// ---------------------------------------------------------------------------
// Kernel 0: windowize+bf16: xw[inp][win][sp][c], weights -> bf16.
// Thread = (1 pixel x 32 channels): 32 independent scalar loads (lane = x,
// perfectly coalesced), pk[k] depends only on loads 2k/2k+1 so loads drain
// with fine-grained vmcnt; store = one contiguous 64B full line.
// ---------------------------------------------------------------------------
__global__ __launch_bounds__(192) void prep_kernel(
    const float* __restrict__ xq, const float* __restrict__ xkv,
    const float* __restrict__ Wq, const float* __restrict__ Wk,
    const float* __restrict__ Wv, const float* __restrict__ Wo,
    b16* __restrict__ xw, b16* __restrict__ Wb)
{
  int bid = blockIdx.x, t = threadIdx.x;
  if (bid < 6144) {                        // 2 inp * 2 b * 192 y * 8 ch-groups
    int grp = bid & 7;                     // channel group of 32
    int rem = bid >> 3;
    int y   = rem % 192;
    int bb  = (rem / 192) & 1;
    int inp = rem / 384;
    int c0  = grp * 32;
    int x   = t;                           // 0..191
    const float* src = (inp ? xkv : xq)
        + (long)(bb * CCH + c0) * PLANE + y * IMG + x;
    u32 pk[16];
#pragma unroll
    for (int k = 0; k < 16; k++) {
      float lo = src[(long)(2 * k)     * PLANE];
      float hi = src[(long)(2 * k + 1) * PLANE];
      pk[k] = (u32)f2bf(lo) | ((u32)f2bf(hi) << 16);
    }
    int win = bb * 144 + (y >> 4) * 12 + (x >> 4);
    int sp  = (y & 15) * 16 + (x & 15);
    b16* dst = xw + (long)inp * XN + (long)win * WELEM + sp * CCH + c0;
    uint4* d4 = reinterpret_cast<uint4*>(dst);
#pragma unroll
    for (int k = 0; k < 4; k++) {
      uint4 q;
      q.x = pk[4 * k + 0]; q.y = pk[4 * k + 1];
      q.z = pk[4 * k + 2]; q.w = pk[4 * k + 3];
      d4[k] = q;
    }
  } else {                                 // weights: 4 * 65536 elements
    int idx = (bid - 6144) * 192 + t;      // 0..32767 valid
    if (idx < 32768) {
      int p = idx >> 13;                   // 0..3 : Wq,Wk,Wv,Wo
      int r = (idx & 8191) * 8;
      const float* src = (p == 0 ? Wq : p == 1 ? Wk : p == 2 ? Wv : Wo) + r;
      b16 o[8];
#pragma unroll
      for (int j = 0; j < 8; j++) o[j] = f2bf(src[j]);
      uint4 pk;
      pk.x = o[0] | ((u32)o[1] << 16);
      pk.y = o[2] | ((u32)o[3] << 16);
      pk.z = o[4] | ((u32)o[5] << 16);
      pk.w = o[6] | ((u32)o[7] << 16);
      *reinterpret_cast<uint4*>(Wb + p * 65536 + r) = pk;
    }
  }
}

// ---------------------------------------------------------------------------
// Shared bt-GEMM core: D[256 m][128 n] = A[256][256] * Bt[128][256]^T
// ---------------------------------------------------------------------------
DEVI void btgemm_core(const b16* __restrict__ Aw, const b16* __restrict__ Bt,
                      b16* as_, b16* bs_, int lane, int wid, f32x4 (&acc)[4][4])
{
  int wm = wid >> 1, wn = wid & 1, quad = lane >> 4, l15 = lane & 15;
  for (int kc = 0; kc < 4; kc++) {
    int c0 = kc * 64;
    __syncthreads();
#pragma unroll
    for (int i = 0; i < 4; i++) {          // stage A: 256 rows x 64 c
      int it  = wid * 4 + i;
      int row = it * 8 + (lane >> 3);
      int g   = (lane & 7) ^ (row & 7);    // slot lane&7 holds group g
      gl2lds16(Aw + row * CCH + c0 + g * 8, as_ + it * 512);
    }
#pragma unroll
    for (int i = 0; i < 2; i++) {          // stage Bt: 128 rows x 64 c
      int it  = wid * 2 + i;
      int row = it * 8 + (lane >> 3);
      int g   = (lane & 7) ^ (row & 7);
      gl2lds16(Bt + row * CCH + c0 + g * 8, bs_ + it * 512);
    }
    __syncthreads();
#pragma unroll
    for (int kk = 0; kk < 2; kk++) {
      short8 af[4], bfv[4];
#pragma unroll
      for (int mt = 0; mt < 4; mt++) {
        int row = wm * 64 + mt * 16 + l15;
        int g   = (kk * 4 + quad) ^ (row & 7);
        af[mt]  = lds8(as_ + row * 64 + g * 8);
      }
#pragma unroll
      for (int nt = 0; nt < 4; nt++) {
        int row = wn * 64 + nt * 16 + l15;
        int g   = (kk * 4 + quad) ^ (row & 7);
        bfv[nt] = lds8(bs_ + row * 64 + g * 8);
      }
#pragma unroll
      for (int mt = 0; mt < 4; mt++)
#pragma unroll
        for (int nt = 0; nt < 4; nt++)
          acc[mt][nt] = __builtin_amdgcn_mfma_f32_16x16x32_bf16(
              af[mt], bfv[nt], acc[mt][nt], 0, 0, 0);
    }
  }
}

// ---------------------------------------------------------------------------
// Kernel A: QKV projection. mode 0/1/2 = Q/K/V.
// Q,K -> [win][s][c] ; V -> transposed [win][c][s]
// Q is pre-scaled by (1/sqrt(32))*log2(e) so attn can exp2 scores directly.
// ---------------------------------------------------------------------------
__global__ __launch_bounds__(512) void qkv_kernel(
    const b16* __restrict__ xw, const b16* __restrict__ Wb,
    const float* __restrict__ bq, const float* __restrict__ bk,
    const float* __restrict__ bv,
    b16* __restrict__ QW, b16* __restrict__ KW, b16* __restrict__ VT)
{
  __shared__ b16 as_[256 * 64];
  __shared__ b16 bs_[128 * 64];
  int bid  = blockIdx.x;
  int mode = bid / 576;
  int rem  = bid % 576;
  int win  = rem >> 1;
  int sp0  = (rem & 1) * 128;
  const b16* Aw = Wb + mode * 65536;
  const b16* Bt = xw + (mode ? XN : 0) + (long)win * WELEM + sp0 * CCH;
  const float* bias = mode == 0 ? bq : mode == 1 ? bk : bv;
  int lane = threadIdx.x & 63, wid = threadIdx.x >> 6;
  int wm = wid >> 1, wn = wid & 1, quad = lane >> 4, l15 = lane & 15;

  f32x4 acc[4][4];
  const f32x4 ZV = {0.f, 0.f, 0.f, 0.f};
#pragma unroll
  for (int i = 0; i < 4; i++)
#pragma unroll
    for (int j = 0; j < 4; j++) acc[i][j] = ZV;

  btgemm_core(Aw, Bt, as_, bs_, lane, wid, acc);

  if (mode < 2) {
    float qs = (mode == 0) ? 0.25505392f : 1.0f;   // (1/sqrt(32))*log2(e)
    b16* Out = (mode == 0 ? QW : KW) + (long)win * WELEM;
#pragma unroll
    for (int mt = 0; mt < 4; mt++) {
      int d0 = wm * 64 + mt * 16 + quad * 4;
      f32x4 bb = *reinterpret_cast<const f32x4*>(bias + d0);
#pragma unroll
      for (int nt = 0; nt < 4; nt++) {
        int sp = sp0 + wn * 64 + nt * 16 + l15;
        uint2 pk;
        pk.x = f2bf((acc[mt][nt][0] + bb[0]) * qs) | ((u32)f2bf((acc[mt][nt][1] + bb[1]) * qs) << 16);
        pk.y = f2bf((acc[mt][nt][2] + bb[2]) * qs) | ((u32)f2bf((acc[mt][nt][3] + bb[3]) * qs) << 16);
        *reinterpret_cast<uint2*>(Out + (long)sp * CCH + d0) = pk;
      }
    }
  } else {
    b16* Out = VT + (long)win * WELEM;
#pragma unroll
    for (int mt = 0; mt < 4; mt++) {
      int d0 = wm * 64 + mt * 16 + quad * 4;
      f32x4 bb = *reinterpret_cast<const f32x4*>(bias + d0);
#pragma unroll
      for (int nt = 0; nt < 4; nt++) {
        int sp = sp0 + wn * 64 + nt * 16 + l15;
#pragma unroll
        for (int r = 0; r < 4; r++)
          Out[(long)(d0 + r) * WTOK + sp] = f2bf(acc[mt][nt][r] + bb[r]);
      }
    }
  }
}

// ---------------------------------------------------------------------------
// Kernel B: attention per (window, head). 4 waves, wave = 64 queries.
// Non-online softmax (S=256, scores O(1), exp2 overflow impossible):
//   P_hat = trunc-bf16(exp2(score')), O = (V^T P_hat^T), l = sum(P_hat),
//   out = O / l.  Sum uses the SAME truncated values as the MFMA.
// ---------------------------------------------------------------------------
__global__ __launch_bounds__(256) void attn_kernel(
    const b16* __restrict__ QW, const b16* __restrict__ KW,
    const b16* __restrict__ VT, b16* __restrict__ AW)
{
  __shared__ b16 ks[256 * 32];     // [key][d]  16 KB
  __shared__ b16 vs[32 * 256];     // [d][s] (16B-group XOR swizzled) 16 KB
  __shared__ b16 ps[4 * 64 * 40];  // per-wave P^T, rows 40 el  20 KB
  int bid = blockIdx.x;
  int win = bid >> 3, head = bid & 7;
  int lane = threadIdx.x & 63, wid = threadIdx.x >> 6;
  int quad = lane >> 4, l15 = lane & 15;

  const b16* Kg = KW + (long)win * WELEM + head * 32;
  const b16* Vg = VT + (long)win * WELEM + head * 32 * WTOK;
  const b16* Qg = QW + (long)win * WELEM + head * 32;

#pragma unroll
  for (int i = 0; i < 4; i++) {            // stage K slice: 256 x 32
    int it  = wid * 4 + i;
    int key = it * 16 + (lane >> 2);
    gl2lds16(Kg + key * CCH + (lane & 3) * 8, ks + it * 512);
  }
#pragma unroll
  for (int i = 0; i < 4; i++) {            // stage V^T slice: 32 x 256, swizzled
    int it   = wid * 4 + i;
    int slot = it * 64 + lane;
    int d    = slot >> 5;
    int gp   = slot & 31;                  // stored slot
    int g    = (gp & 24) | ((gp & 7) ^ (d & 7));  // logical 16B group
    gl2lds16(Vg + d * WTOK + g * 8, vs + it * 512);
  }

  short8 qf[4];                            // Q fragments stay in registers
#pragma unroll
  for (int qt = 0; qt < 4; qt++) {
    int q = wid * 64 + qt * 16 + l15;
    qf[qt] = *reinterpret_cast<const short8*>(Qg + (long)q * CCH + quad * 8);
  }

  __syncthreads();

  const f32x4 ZV = {0.f, 0.f, 0.f, 0.f};
  f32x4 oacc[2][4];
#pragma unroll
  for (int mt = 0; mt < 2; mt++)
#pragma unroll
    for (int qt = 0; qt < 4; qt++) oacc[mt][qt] = ZV;
  float psum[4];
#pragma unroll
  for (int qt = 0; qt < 4; qt++) psum[qt] = 0.f;

  b16* psw = ps + wid * (64 * 40);

  for (int kb = 0; kb < 8; kb++) {         // 32 keys per iteration
    int k0 = kb * 32;
    short8 kf[2];
#pragma unroll
    for (int km = 0; km < 2; km++)
      kf[km] = lds8(ks + (k0 + km * 16 + l15) * 32 + quad * 8);
    f32x4 sc[2][4];                        // scores^T[key][q], pre-scaled
#pragma unroll
    for (int km = 0; km < 2; km++)
#pragma unroll
      for (int qt = 0; qt < 4; qt++)
        sc[km][qt] = __builtin_amdgcn_mfma_f32_16x16x32_bf16(kf[km], qf[qt], ZV, 0, 0, 0);

#pragma unroll
    for (int qt = 0; qt < 4; qt++) {
      int qrow = qt * 16 + l15;
#pragma unroll
      for (int km = 0; km < 2; km++) {
        u32 u0 = __float_as_uint(__builtin_amdgcn_exp2f(sc[km][qt][0])) & 0xffff0000u;
        u32 u1 = __float_as_uint(__builtin_amdgcn_exp2f(sc[km][qt][1])) & 0xffff0000u;
        u32 u2 = __float_as_uint(__builtin_amdgcn_exp2f(sc[km][qt][2])) & 0xffff0000u;
        u32 u3 = __float_as_uint(__builtin_amdgcn_exp2f(sc[km][qt][3])) & 0xffff0000u;
        psum[qt] += (__uint_as_float(u0) + __uint_as_float(u1))
                  + (__uint_as_float(u2) + __uint_as_float(u3));
        uint2 pk;
        pk.x = (u0 >> 16) | u1;
        pk.y = (u2 >> 16) | u3;
        *reinterpret_cast<uint2*>(psw + qrow * 40 + km * 16 + quad * 4) = pk;
      }
    }
    short8 vf[2], pf[4];
#pragma unroll
    for (int mt = 0; mt < 2; mt++) {       // V^T fragments (de-swizzle)
      int d  = mt * 16 + l15;
      int gl = kb * 4 + quad;
      int gs = (gl & 24) | ((gl & 7) ^ (d & 7));
      vf[mt] = lds8(vs + d * WTOK + gs * 8);
    }
#pragma unroll
    for (int qt = 0; qt < 4; qt++)
      pf[qt] = lds8(psw + (qt * 16 + l15) * 40 + quad * 8);
#pragma unroll
    for (int mt = 0; mt < 2; mt++)
#pragma unroll
      for (int qt = 0; qt < 4; qt++)
        oacc[mt][qt] = __builtin_amdgcn_mfma_f32_16x16x32_bf16(
            vf[mt], pf[qt], oacc[mt][qt], 0, 0, 0);
  }

  b16* Og = AW + (long)win * WELEM + head * 32;   // AW[win][s][c]
#pragma unroll
  for (int qt = 0; qt < 4; qt++) {
    float l = psum[qt];
    l += __shfl_xor(l, 16);
    l += __shfl_xor(l, 32);
    float rl = __builtin_amdgcn_rcpf(l);
    int q = wid * 64 + qt * 16 + l15;
#pragma unroll
    for (int mt = 0; mt < 2; mt++) {
      uint2 pk;
      pk.x = f2bf(oacc[mt][qt][0] * rl) | ((u32)f2bf(oacc[mt][qt][1] * rl) << 16);
      pk.y = f2bf(oacc[mt][qt][2] * rl) | ((u32)f2bf(oacc[mt][qt][3] * rl) << 16);
      *reinterpret_cast<uint2*>(Og + (long)q * CCH + mt * 16 + quad * 4) = pk;
    }
  }
}

// ---------------------------------------------------------------------------
// Kernel C: output projection, D[d][sp] -> natural (B,C,H,W) fp32 + bias
// ---------------------------------------------------------------------------
__global__ __launch_bounds__(512) void oproj_kernel(
    const b16* __restrict__ AW, const b16* __restrict__ Wb,
    const float* __restrict__ bo, float* __restrict__ out)
{
  __shared__ b16 as_[256 * 64];
  __shared__ b16 bs_[128 * 64];
  int bid = blockIdx.x;
  int win = bid >> 1;
  int sp0 = (bid & 1) * 128;
  const b16* Aw = Wb + 3 * 65536;
  const b16* Bt = AW + (long)win * WELEM + sp0 * CCH;
  int lane = threadIdx.x & 63, wid = threadIdx.x >> 6;
  int wm = wid >> 1, wn = wid & 1, quad = lane >> 4, l15 = lane & 15;

  f32x4 acc[4][4];
  const f32x4 ZV = {0.f, 0.f, 0.f, 0.f};
#pragma unroll
  for (int i = 0; i < 4; i++)
#pragma unroll
    for (int j = 0; j < 4; j++) acc[i][j] = ZV;

  btgemm_core(Aw, Bt, as_, bs_, lane, wid, acc);

  int b = win / 144, wh = (win / 12) % 12, ww = win % 12;
#pragma unroll
  for (int mt = 0; mt < 4; mt++) {
    int d0 = wm * 64 + mt * 16 + quad * 4;
    f32x4 bb = *reinterpret_cast<const f32x4*>(bo + d0);
#pragma unroll
    for (int nt = 0; nt < 4; nt++) {
      int sp = sp0 + wn * 64 + nt * 16 + l15;
      int y = sp >> 4, x = sp & 15;
      float* op = out + (long)b * CCH * PLANE + (long)(wh * 16 + y) * IMG + ww * 16 + x;
#pragma unroll
      for (int r = 0; r < 4; r++)
        op[(long)(d0 + r) * PLANE] = acc[mt][nt][r] + bb[r];
    }
  }
}

// ---------------------------------------------------------------------------
extern "C" void kernel_launch(void* const* d_in, const int* in_sizes, int n_in,
                              void* d_out, int out_size, void* d_ws, size_t ws_size,
                              hipStream_t stream)
{
  const float* xq  = (const float*)d_in[0];
  const float* xkv = (const float*)d_in[1];
  const float* Wq  = (const float*)d_in[2];
  const float* bq  = (const float*)d_in[3];
  const float* Wk  = (const float*)d_in[4];
  const float* bk  = (const float*)d_in[5];
  const float* Wv  = (const float*)d_in[6];
  const float* bv  = (const float*)d_in[7];
  const float* Wo  = (const float*)d_in[8];
  const float* bo  = (const float*)d_in[9];

  // workspace layout (bytes): needs ~189.3 MB
  char* ws = (char*)d_ws;
  b16* xw = (b16*)ws;                       // 2 * 18874368 * 2 = 75,497,472
  b16* QW = (b16*)(ws + 75497472);          // 37,748,736
  b16* KW = (b16*)(ws + 113246208);         // 37,748,736
  b16* VT = (b16*)(ws + 150994944);         // 37,748,736
  b16* Wb = (b16*)(ws + 188743680);         // 524,288
  b16* AW = xw;                             // alias: xw dead after qkv_kernel
  float* out = (float*)d_out;

  prep_kernel<<<dim3(6320), dim3(192), 0, stream>>>(xq, xkv, Wq, Wk, Wv, Wo, xw, Wb);
  qkv_kernel<<<dim3(1728), dim3(512), 0, stream>>>(xw, Wb, bq, bk, bv, QW, KW, VT);
  attn_kernel<<<dim3(2304), dim3(256), 0, stream>>>(QW, KW, VT, AW);
  oproj_kernel<<<dim3(576), dim3(512), 0, stream>>>(AW, Wb, bo, out);
}

// Round 6
// 363.579 us; speedup vs baseline: 1.0185x; 1.0185x over previous
//
#include <hip/hip_runtime.h>
#include <stdint.h>

typedef unsigned short b16;
typedef unsigned int   u32;
typedef __attribute__((ext_vector_type(8))) short short8;   // 8 x bf16 (4 VGPR)
typedef __attribute__((ext_vector_type(4))) float f32x4;    // 4 x fp32 acc

#define DEVI static __device__ __forceinline__

constexpr int CCH   = 256;           // channels
constexpr int IMG   = 192;           // H = W
constexpr int PLANE = IMG * IMG;     // 36864
constexpr int WTOK  = 256;           // tokens per 16x16 window
constexpr int WELEM = WTOK * CCH;    // 65536 elements per window slab
constexpr long XN   = 18874368;      // elements per input tensor (2*256*192*192)

DEVI b16 f2bf(float f) {             // fp32 -> bf16 round-to-nearest-even
  u32 u = __float_as_uint(f);
  u += 0x7fffu + ((u >> 16) & 1u);
  return (b16)(u >> 16);
}

// async global->LDS, 16B per lane; LDS dest = wave-uniform base + lane*16
DEVI void gl2lds16(const void* g, void* l) {
  __builtin_amdgcn_global_load_lds(
      (const __attribute__((address_space(1))) u32*)g,
      (__attribute__((address_space(3))) u32*)l, 16, 0, 0);
}

DEVI short8 lds8(const b16* p) { return *reinterpret_cast<const short8*>(p); }

// ---------------------------------------------------------------------------
// Kernel 0: windowize+bf16: xw[inp][win][sp][c], weights -> bf16.
// Block = one y-row x 32 channels. Staging is ASYNC global_load_lds (no dest
// registers -> all 32 row-loads in flight; immune to compiler waitcnt
// pairing, which capped R2/R4 at ~1.6 TB/s). Transpose happens on the LDS
// read side; global 16B-group XOR swizzle makes the strided ds_read_b32
// pattern 2-way max per bank (free). Stores: one 64B full line per thread.
// LDS row pitch = 256 floats (1 KB): lanes 48..63 stage a duplicate of
// groups 0..15 into the pad so no exec-masking of the async load is needed.
// GRID: 6144 pixel blocks + ceil(32768/192)=171 weight blocks = 6315.
// (R5 failed with 6166: weight tail under-launched -> poisoned weights.)
// ---------------------------------------------------------------------------
__global__ __launch_bounds__(192) void prep_kernel(
    const float* __restrict__ xq, const float* __restrict__ xkv,
    const float* __restrict__ Wq, const float* __restrict__ Wk,
    const float* __restrict__ Wv, const float* __restrict__ Wo,
    b16* __restrict__ xw, b16* __restrict__ Wb)
{
  __shared__ float ls[32 * 256];           // 32 KB, pitch 1 KB per c-row
  int bid = blockIdx.x, t = threadIdx.x;
  if (bid < 6144) {                        // 2 inp * 2 b * 192 y * 8 ch-groups
    int grp = bid & 7;                     // channel group of 32
    int rem = bid >> 3;
    int y   = rem % 192;
    int bb  = (rem / 192) & 1;
    int inp = rem / 384;
    int c0  = grp * 32;
    const float* base = (inp ? xkv : xq) + (long)(bb * CCH + c0) * PLANE + (long)y * IMG;
    int lane = t & 63, wid = t >> 6;
    // stage 32 rows (768B each) async; row c: lane l holds 16B group
    //   g = (l&0x30) | ((l&15) ^ (c&15))   for l<48  (XOR swizzle)
    //   g = l-48                           for l>=48 (dup into pad)
    int gA = (lane < 48) ? ((lane & 0x30) | (lane & 15)) : (lane - 48);
    int gX = (lane < 48) ? 15 : 0;         // xor-mask applicability
    for (int c = wid; c < 32; c += 3) {
      int g = gA ^ (gX & c);
      gl2lds16(base + (long)c * PLANE + g * 4, ls + c * 256);
    }
    __syncthreads();
    // read back: thread = px; logical group of px is g=px>>2, stored at
    // slot = (g&0x30) | ((g&15)^(c&15)); float offset slot*4 + (px&3)
    int px  = t;
    int shi = (px >> 2) & 0x30;            // segment bits of group
    int g4  = (px >> 2) & 15;
    int po  = px & 3;
    u32 pk[16];
#pragma unroll
    for (int k = 0; k < 16; k++) {
      int cl = 2 * k, ch = 2 * k + 1;
      float lo = ls[cl * 256 + ((shi | (g4 ^ (cl & 15))) << 2) + po];
      float hi = ls[ch * 256 + ((shi | (g4 ^ (ch & 15))) << 2) + po];
      pk[k] = (u32)f2bf(lo) | ((u32)f2bf(hi) << 16);
    }
    int win = bb * 144 + (y >> 4) * 12 + (px >> 4);
    int sp  = (y & 15) * 16 + (px & 15);
    b16* dst = xw + (long)inp * XN + (long)win * WELEM + sp * CCH + c0;
    uint4* d4 = reinterpret_cast<uint4*>(dst);
#pragma unroll
    for (int k = 0; k < 4; k++) {
      uint4 q;
      q.x = pk[4 * k + 0]; q.y = pk[4 * k + 1];
      q.z = pk[4 * k + 2]; q.w = pk[4 * k + 3];
      d4[k] = q;
    }
  } else {                                 // weights: 4 * 65536 elements
    int idx = (bid - 6144) * 192 + t;      // 0..32767 valid
    if (idx < 32768) {
      int p = idx >> 13;                   // 0..3 : Wq,Wk,Wv,Wo
      int r = (idx & 8191) * 8;
      const float* src = (p == 0 ? Wq : p == 1 ? Wk : p == 2 ? Wv : Wo) + r;
      b16 o[8];
#pragma unroll
      for (int j = 0; j < 8; j++) o[j] = f2bf(src[j]);
      uint4 pk;
      pk.x = o[0] | ((u32)o[1] << 16);
      pk.y = o[2] | ((u32)o[3] << 16);
      pk.z = o[4] | ((u32)o[5] << 16);
      pk.w = o[6] | ((u32)o[7] << 16);
      *reinterpret_cast<uint4*>(Wb + p * 65536 + r) = pk;
    }
  }
}

// ---------------------------------------------------------------------------
// Shared bt-GEMM core: D[256 m][128 n] = A[256][256] * Bt[128][256]^T
// ---------------------------------------------------------------------------
DEVI void btgemm_core(const b16* __restrict__ Aw, const b16* __restrict__ Bt,
                      b16* as_, b16* bs_, int lane, int wid, f32x4 (&acc)[4][4])
{
  int wm = wid >> 1, wn = wid & 1, quad = lane >> 4, l15 = lane & 15;
  for (int kc = 0; kc < 4; kc++) {
    int c0 = kc * 64;
    __syncthreads();
#pragma unroll
    for (int i = 0; i < 4; i++) {          // stage A: 256 rows x 64 c
      int it  = wid * 4 + i;
      int row = it * 8 + (lane >> 3);
      int g   = (lane & 7) ^ (row & 7);    // slot lane&7 holds group g
      gl2lds16(Aw + row * CCH + c0 + g * 8, as_ + it * 512);
    }
#pragma unroll
    for (int i = 0; i < 2; i++) {          // stage Bt: 128 rows x 64 c
      int it  = wid * 2 + i;
      int row = it * 8 + (lane >> 3);
      int g   = (lane & 7) ^ (row & 7);
      gl2lds16(Bt + row * CCH + c0 + g * 8, bs_ + it * 512);
    }
    __syncthreads();
#pragma unroll
    for (int kk = 0; kk < 2; kk++) {
      short8 af[4], bfv[4];
#pragma unroll
      for (int mt = 0; mt < 4; mt++) {
        int row = wm * 64 + mt * 16 + l15;
        int g   = (kk * 4 + quad) ^ (row & 7);
        af[mt]  = lds8(as_ + row * 64 + g * 8);
      }
#pragma unroll
      for (int nt = 0; nt < 4; nt++) {
        int row = wn * 64 + nt * 16 + l15;
        int g   = (kk * 4 + quad) ^ (row & 7);
        bfv[nt] = lds8(bs_ + row * 64 + g * 8);
      }
#pragma unroll
      for (int mt = 0; mt < 4; mt++)
#pragma unroll
        for (int nt = 0; nt < 4; nt++)
          acc[mt][nt] = __builtin_amdgcn_mfma_f32_16x16x32_bf16(
              af[mt], bfv[nt], acc[mt][nt], 0, 0, 0);
    }
  }
}

// ---------------------------------------------------------------------------
// Kernel A: QKV projection. mode 0/1/2 = Q/K/V.
// Q,K -> [win][s][c] ; V -> transposed [win][c][s]
// Q is pre-scaled by (1/sqrt(32))*log2(e) so attn can exp2 scores directly.
// ---------------------------------------------------------------------------
__global__ __launch_bounds__(512) void qkv_kernel(
    const b16* __restrict__ xw, const b16* __restrict__ Wb,
    const float* __restrict__ bq, const float* __restrict__ bk,
    const float* __restrict__ bv,
    b16* __restrict__ QW, b16* __restrict__ KW, b16* __restrict__ VT)
{
  __shared__ b16 as_[256 * 64];
  __shared__ b16 bs_[128 * 64];
  int bid  = blockIdx.x;
  int mode = bid / 576;
  int rem  = bid % 576;
  int win  = rem >> 1;
  int sp0  = (rem & 1) * 128;
  const b16* Aw = Wb + mode * 65536;
  const b16* Bt = xw + (mode ? XN : 0) + (long)win * WELEM + sp0 * CCH;
  const float* bias = mode == 0 ? bq : mode == 1 ? bk : bv;
  int lane = threadIdx.x & 63, wid = threadIdx.x >> 6;
  int wm = wid >> 1, wn = wid & 1, quad = lane >> 4, l15 = lane & 15;

  f32x4 acc[4][4];
  const f32x4 ZV = {0.f, 0.f, 0.f, 0.f};
#pragma unroll
  for (int i = 0; i < 4; i++)
#pragma unroll
    for (int j = 0; j < 4; j++) acc[i][j] = ZV;

  btgemm_core(Aw, Bt, as_, bs_, lane, wid, acc);

  if (mode < 2) {
    float qs = (mode == 0) ? 0.25505392f : 1.0f;   // (1/sqrt(32))*log2(e)
    b16* Out = (mode == 0 ? QW : KW) + (long)win * WELEM;
#pragma unroll
    for (int mt = 0; mt < 4; mt++) {
      int d0 = wm * 64 + mt * 16 + quad * 4;
      f32x4 bb = *reinterpret_cast<const f32x4*>(bias + d0);
#pragma unroll
      for (int nt = 0; nt < 4; nt++) {
        int sp = sp0 + wn * 64 + nt * 16 + l15;
        uint2 pk;
        pk.x = f2bf((acc[mt][nt][0] + bb[0]) * qs) | ((u32)f2bf((acc[mt][nt][1] + bb[1]) * qs) << 16);
        pk.y = f2bf((acc[mt][nt][2] + bb[2]) * qs) | ((u32)f2bf((acc[mt][nt][3] + bb[3]) * qs) << 16);
        *reinterpret_cast<uint2*>(Out + (long)sp * CCH + d0) = pk;
      }
    }
  } else {
    b16* Out = VT + (long)win * WELEM;
#pragma unroll
    for (int mt = 0; mt < 4; mt++) {
      int d0 = wm * 64 + mt * 16 + quad * 4;
      f32x4 bb = *reinterpret_cast<const f32x4*>(bias + d0);
#pragma unroll
      for (int nt = 0; nt < 4; nt++) {
        int sp = sp0 + wn * 64 + nt * 16 + l15;
#pragma unroll
        for (int r = 0; r < 4; r++)
          Out[(long)(d0 + r) * WTOK + sp] = f2bf(acc[mt][nt][r] + bb[r]);
      }
    }
  }
}

// ---------------------------------------------------------------------------
// Kernel B: attention per (window, head). 4 waves, wave = 64 queries.
// Non-online softmax (S=256, scores O(1), exp2 overflow impossible):
//   P_hat = trunc-bf16(exp2(score')), O = (V^T P_hat^T), l = sum(P_hat),
//   out = O / l.  Sum uses the SAME truncated values as the MFMA.
// ---------------------------------------------------------------------------
__global__ __launch_bounds__(256) void attn_kernel(
    const b16* __restrict__ QW, const b16* __restrict__ KW,
    const b16* __restrict__ VT, b16* __restrict__ AW)
{
  __shared__ b16 ks[256 * 32];     // [key][d]  16 KB
  __shared__ b16 vs[32 * 256];     // [d][s] (16B-group XOR swizzled) 16 KB
  __shared__ b16 ps[4 * 64 * 40];  // per-wave P^T, rows 40 el  20 KB
  int bid = blockIdx.x;
  int win = bid >> 3, head = bid & 7;
  int lane = threadIdx.x & 63, wid = threadIdx.x >> 6;
  int quad = lane >> 4, l15 = lane & 15;

  const b16* Kg = KW + (long)win * WELEM + head * 32;
  const b16* Vg = VT + (long)win * WELEM + head * 32 * WTOK;
  const b16* Qg = QW + (long)win * WELEM + head * 32;

#pragma unroll
  for (int i = 0; i < 4; i++) {            // stage K slice: 256 x 32
    int it  = wid * 4 + i;
    int key = it * 16 + (lane >> 2);
    gl2lds16(Kg + key * CCH + (lane & 3) * 8, ks + it * 512);
  }
#pragma unroll
  for (int i = 0; i < 4; i++) {            // stage V^T slice: 32 x 256, swizzled
    int it   = wid * 4 + i;
    int slot = it * 64 + lane;
    int d    = slot >> 5;
    int gp   = slot & 31;                  // stored slot
    int g    = (gp & 24) | ((gp & 7) ^ (d & 7));  // logical 16B group
    gl2lds16(Vg + d * WTOK + g * 8, vs + it * 512);
  }

  short8 qf[4];                            // Q fragments stay in registers
#pragma unroll
  for (int qt = 0; qt < 4; qt++) {
    int q = wid * 64 + qt * 16 + l15;
    qf[qt] = *reinterpret_cast<const short8*>(Qg + (long)q * CCH + quad * 8);
  }

  __syncthreads();

  const f32x4 ZV = {0.f, 0.f, 0.f, 0.f};
  f32x4 oacc[2][4];
#pragma unroll
  for (int mt = 0; mt < 2; mt++)
#pragma unroll
    for (int qt = 0; qt < 4; qt++) oacc[mt][qt] = ZV;
  float psum[4];
#pragma unroll
  for (int qt = 0; qt < 4; qt++) psum[qt] = 0.f;

  b16* psw = ps + wid * (64 * 40);

  for (int kb = 0; kb < 8; kb++) {         // 32 keys per iteration
    int k0 = kb * 32;
    short8 kf[2];
#pragma unroll
    for (int km = 0; km < 2; km++)
      kf[km] = lds8(ks + (k0 + km * 16 + l15) * 32 + quad * 8);
    f32x4 sc[2][4];                        // scores^T[key][q], pre-scaled
#pragma unroll
    for (int km = 0; km < 2; km++)
#pragma unroll
      for (int qt = 0; qt < 4; qt++)
        sc[km][qt] = __builtin_amdgcn_mfma_f32_16x16x32_bf16(kf[km], qf[qt], ZV, 0, 0, 0);

#pragma unroll
    for (int qt = 0; qt < 4; qt++) {
      int qrow = qt * 16 + l15;
#pragma unroll
      for (int km = 0; km < 2; km++) {
        u32 u0 = __float_as_uint(__builtin_amdgcn_exp2f(sc[km][qt][0])) & 0xffff0000u;
        u32 u1 = __float_as_uint(__builtin_amdgcn_exp2f(sc[km][qt][1])) & 0xffff0000u;
        u32 u2 = __float_as_uint(__builtin_amdgcn_exp2f(sc[km][qt][2])) & 0xffff0000u;
        u32 u3 = __float_as_uint(__builtin_amdgcn_exp2f(sc[km][qt][3])) & 0xffff0000u;
        psum[qt] += (__uint_as_float(u0) + __uint_as_float(u1))
                  + (__uint_as_float(u2) + __uint_as_float(u3));
        uint2 pk;
        pk.x = (u0 >> 16) | u1;
        pk.y = (u2 >> 16) | u3;
        *reinterpret_cast<uint2*>(psw + qrow * 40 + km * 16 + quad * 4) = pk;
      }
    }
    short8 vf[2], pf[4];
#pragma unroll
    for (int mt = 0; mt < 2; mt++) {       // V^T fragments (de-swizzle)
      int d  = mt * 16 + l15;
      int gl = kb * 4 + quad;
      int gs = (gl & 24) | ((gl & 7) ^ (d & 7));
      vf[mt] = lds8(vs + d * WTOK + gs * 8);
    }
#pragma unroll
    for (int qt = 0; qt < 4; qt++)
      pf[qt] = lds8(psw + (qt * 16 + l15) * 40 + quad * 8);
#pragma unroll
    for (int mt = 0; mt < 2; mt++)
#pragma unroll
      for (int qt = 0; qt < 4; qt++)
        oacc[mt][qt] = __builtin_amdgcn_mfma_f32_16x16x32_bf16(
            vf[mt], pf[qt], oacc[mt][qt], 0, 0, 0);
  }

  b16* Og = AW + (long)win * WELEM + head * 32;   // AW[win][s][c]
#pragma unroll
  for (int qt = 0; qt < 4; qt++) {
    float l = psum[qt];
    l += __shfl_xor(l, 16);
    l += __shfl_xor(l, 32);
    float rl = __builtin_amdgcn_rcpf(l);
    int q = wid * 64 + qt * 16 + l15;
#pragma unroll
    for (int mt = 0; mt < 2; mt++) {
      uint2 pk;
      pk.x = f2bf(oacc[mt][qt][0] * rl) | ((u32)f2bf(oacc[mt][qt][1] * rl) << 16);
      pk.y = f2bf(oacc[mt][qt][2] * rl) | ((u32)f2bf(oacc[mt][qt][3] * rl) << 16);
      *reinterpret_cast<uint2*>(Og + (long)q * CCH + mt * 16 + quad * 4) = pk;
    }
  }
}

// ---------------------------------------------------------------------------
// Kernel C: output projection, D[d][sp] -> natural (B,C,H,W) fp32 + bias
// ---------------------------------------------------------------------------
__global__ __launch_bounds__(512) void oproj_kernel(
    const b16* __restrict__ AW, const b16* __restrict__ Wb,
    const float* __restrict__ bo, float* __restrict__ out)
{
  __shared__ b16 as_[256 * 64];
  __shared__ b16 bs_[128 * 64];
  int bid = blockIdx.x;
  int win = bid >> 1;
  int sp0 = (bid & 1) * 128;
  const b16* Aw = Wb + 3 * 65536;
  const b16* Bt = AW + (long)win * WELEM + sp0 * CCH;
  int lane = threadIdx.x & 63, wid = threadIdx.x >> 6;
  int wm = wid >> 1, wn = wid & 1, quad = lane >> 4, l15 = lane & 15;

  f32x4 acc[4][4];
  const f32x4 ZV = {0.f, 0.f, 0.f, 0.f};
#pragma unroll
  for (int i = 0; i < 4; i++)
#pragma unroll
    for (int j = 0; j < 4; j++) acc[i][j] = ZV;

  btgemm_core(Aw, Bt, as_, bs_, lane, wid, acc);

  int b = win / 144, wh = (win / 12) % 12, ww = win % 12;
#pragma unroll
  for (int mt = 0; mt < 4; mt++) {
    int d0 = wm * 64 + mt * 16 + quad * 4;
    f32x4 bb = *reinterpret_cast<const f32x4*>(bo + d0);
#pragma unroll
    for (int nt = 0; nt < 4; nt++) {
      int sp = sp0 + wn * 64 + nt * 16 + l15;
      int y = sp >> 4, x = sp & 15;
      float* op = out + (long)b * CCH * PLANE + (long)(wh * 16 + y) * IMG + ww * 16 + x;
#pragma unroll
      for (int r = 0; r < 4; r++)
        op[(long)(d0 + r) * PLANE] = acc[mt][nt][r] + bb[r];
    }
  }
}

// ---------------------------------------------------------------------------
extern "C" void kernel_launch(void* const* d_in, const int* in_sizes, int n_in,
                              void* d_out, int out_size, void* d_ws, size_t ws_size,
                              hipStream_t stream)
{
  const float* xq  = (const float*)d_in[0];
  const float* xkv = (const float*)d_in[1];
  const float* Wq  = (const float*)d_in[2];
  const float* bq  = (const float*)d_in[3];
  const float* Wk  = (const float*)d_in[4];
  const float* bk  = (const float*)d_in[5];
  const float* Wv  = (const float*)d_in[6];
  const float* bv  = (const float*)d_in[7];
  const float* Wo  = (const float*)d_in[8];
  const float* bo  = (const float*)d_in[9];

  // workspace layout (bytes): needs ~189.3 MB
  char* ws = (char*)d_ws;
  b16* xw = (b16*)ws;                       // 2 * 18874368 * 2 = 75,497,472
  b16* QW = (b16*)(ws + 75497472);          // 37,748,736
  b16* KW = (b16*)(ws + 113246208);         // 37,748,736
  b16* VT = (b16*)(ws + 150994944);         // 37,748,736
  b16* Wb = (b16*)(ws + 188743680);         // 524,288
  b16* AW = xw;                             // alias: xw dead after qkv_kernel
  float* out = (float*)d_out;

  prep_kernel<<<dim3(6315), dim3(192), 0, stream>>>(xq, xkv, Wq, Wk, Wv, Wo, xw, Wb);
  qkv_kernel<<<dim3(1728), dim3(512), 0, stream>>>(xw, Wb, bq, bk, bv, QW, KW, VT);
  attn_kernel<<<dim3(2304), dim3(256), 0, stream>>>(QW, KW, VT, AW);
  oproj_kernel<<<dim3(576), dim3(512), 0, stream>>>(AW, Wb, bo, out);
}

// Round 7
// 346.098 us; speedup vs baseline: 1.0700x; 1.0505x over previous
//
#include <hip/hip_runtime.h>
#include <stdint.h>

typedef unsigned short b16;
typedef unsigned int   u32;
typedef __attribute__((ext_vector_type(8))) short short8;   // 8 x bf16 (4 VGPR)
typedef __attribute__((ext_vector_type(4))) float f32x4;    // 4 x fp32 acc

#define DEVI static __device__ __forceinline__

constexpr int CCH   = 256;           // channels
constexpr int IMG   = 192;           // H = W
constexpr int PLANE = IMG * IMG;     // 36864
constexpr int WTOK  = 256;           // tokens per 16x16 window
constexpr int WELEM = WTOK * CCH;    // 65536 elements per window slab
constexpr long XN   = 18874368;      // elements per input tensor (2*256*192*192)

DEVI b16 f2bf(float f) {             // fp32 -> bf16 round-to-nearest-even
  u32 u = __float_as_uint(f);
  u += 0x7fffu + ((u >> 16) & 1u);
  return (b16)(u >> 16);
}

// async global->LDS, 16B per lane; LDS dest = wave-uniform base + lane*16
DEVI void gl2lds16(const void* g, void* l) {
  __builtin_amdgcn_global_load_lds(
      (const __attribute__((address_space(1))) u32*)g,
      (__attribute__((address_space(3))) u32*)l, 16, 0, 0);
}

DEVI short8 lds8(const b16* p) { return *reinterpret_cast<const short8*>(p); }

// ---------------------------------------------------------------------------
// Kernel 0a: weights -> bf16 (tiny, 1.3 MB traffic)
// ---------------------------------------------------------------------------
__global__ __launch_bounds__(256) void wprep_kernel(
    const float* __restrict__ Wq, const float* __restrict__ Wk,
    const float* __restrict__ Wv, const float* __restrict__ Wo,
    b16* __restrict__ Wb)
{
  int idx = blockIdx.x * 256 + threadIdx.x;   // 0..32767
  int p = idx >> 13;                          // 0..3 : Wq,Wk,Wv,Wo
  int r = (idx & 8191) * 8;
  const float* src = (p == 0 ? Wq : p == 1 ? Wk : p == 2 ? Wv : Wo) + r;
  b16 o[8];
#pragma unroll
  for (int j = 0; j < 8; j++) o[j] = f2bf(src[j]);
  uint4 pk;
  pk.x = o[0] | ((u32)o[1] << 16);
  pk.y = o[2] | ((u32)o[3] << 16);
  pk.z = o[4] | ((u32)o[5] << 16);
  pk.w = o[6] | ((u32)o[7] << 16);
  *reinterpret_cast<uint4*>(Wb + p * 65536 + r) = pk;
}

// ---------------------------------------------------------------------------
// Kernel 0b: windowize+bf16: xw[inp][win][sp][c].
// PERSISTENT + DOUBLE-BUFFERED: 768 blocks x 8 tiles. While tile i is
// converted+stored, tile i+1's global_load_lds burst is already in flight;
// waits are fine-grained s_waitcnt vmcnt(N) + raw s_barrier (never a full
// vmcnt(0) drain mid-pipeline). Per-wave vmcnt bookkeeping: every wave
// issues exactly 8 loads/tile and 3 stores/tile.
//   tile = (inp, b, y, grp32): stage 32 rows x 192 px fp32 (XOR-swizzled
//   16B groups, pitch 208 floats), convert on LDS read side, store 16B
//   lines (4 lanes = one 64B full line).
// ---------------------------------------------------------------------------
constexpr int PREP_NB = 768;         // blocks (3/CU by LDS)
constexpr int PREP_NT = 8;           // tiles per block; NB*NT = 6144
constexpr int LPITCH  = 208;         // floats per channel-row (832 B)

__global__ __launch_bounds__(256) void prep_kernel(
    const float* __restrict__ xq, const float* __restrict__ xkv,
    b16* __restrict__ xw)
{
  __shared__ float ls[2][32 * LPITCH];       // 2 x 26624 B = 53248 B
  const int bid = blockIdx.x, t = threadIdx.x;
  const int lane = t & 63, w = t >> 6;

  // staging lane->slot map: lane l holds 16B group g = (l&0x30)|((l&15)^(c&15))
  // lanes 48..51 fill the 64B row pad (dup of groups 0..3); lanes >=52 masked.
  const int gA = (lane < 48) ? ((lane & 0x30) | (lane & 15)) : (lane - 48);
  const int gX = (lane < 48) ? 15 : 0;
  const bool ld_act = (lane < 52);

  for (int i = 0; i < PREP_NT; i++) {
    // ---- issue tile i+1 into buffer (i+1)&1 (its prior contents were
    //      fully read in iter i-1; trailing barrier guarantees safety)
    if (i == 0) {                            // prologue: issue tile 0
      int tile = bid;
      int grp = tile & 7, rem = tile >> 3;
      int y = rem % 192, bb = (rem / 192) & 1, inp = rem / 384;
      const float* base = (inp ? xkv : xq)
          + (long)(bb * CCH + grp * 32) * PLANE + (long)y * IMG;
      if (ld_act) {
#pragma unroll
        for (int j = 0; j < 8; j++) {
          int c = w * 8 + j;
          int g = gA ^ (gX & c);
          gl2lds16(base + (long)c * PLANE + g * 4, &ls[0][c * LPITCH]);
        }
      }
    }
    if (i + 1 < PREP_NT) {
      int tile = bid + (i + 1) * PREP_NB;
      int grp = tile & 7, rem = tile >> 3;
      int y = rem % 192, bb = (rem / 192) & 1, inp = rem / 384;
      const float* base = (inp ? xkv : xq)
          + (long)(bb * CCH + grp * 32) * PLANE + (long)y * IMG;
      if (ld_act) {
#pragma unroll
        for (int j = 0; j < 8; j++) {
          int c = w * 8 + j;
          int g = gA ^ (gX & c);
          gl2lds16(base + (long)c * PLANE + g * 4, &ls[(i + 1) & 1][c * LPITCH]);
        }
      }
    }
    // ---- wait for tile i's 8 loads (oldest), keep tile i+1's in flight
    __builtin_amdgcn_sched_barrier(0);
    if (i == 0)                __builtin_amdgcn_s_waitcnt(0xF78); // vmcnt(8):  [L0 8 | L1 8]
    else if (i + 1 < PREP_NT)  __builtin_amdgcn_s_waitcnt(0xF7B); // vmcnt(11): [Li 8 | S 3 | Li+1 8]
    else                       __builtin_amdgcn_s_waitcnt(0xF73); // vmcnt(3):  [Li 8 | S 3]
    __builtin_amdgcn_s_barrier();
    __builtin_amdgcn_sched_barrier(0);

    // ---- process tile i from buffer i&1
    {
      int tile = bid + i * PREP_NB;
      int grp = tile & 7, rem = tile >> 3;
      int y = rem % 192, bb = (rem / 192) & 1, inp = rem / 384;
      const float* lsb = ls[i & 1];
#pragma unroll
      for (int m = 0; m < 3; m++) {          // 768 (px,k) items / 256 threads
        int idx = t + m * 256;
        int px = idx >> 2, k = idx & 3;      // px 0..191, k = 16B quarter
        int shi = (px >> 2) & 0x30, g4 = (px >> 2) & 15, po = px & 3;
        u32 d[4];
#pragma unroll
        for (int jj = 0; jj < 4; jj++) {
          int cl = k * 8 + 2 * jj, ch = cl + 1;
          float lo = lsb[cl * LPITCH + ((shi | (g4 ^ (cl & 15))) << 2) + po];
          float hi = lsb[ch * LPITCH + ((shi | (g4 ^ (ch & 15))) << 2) + po];
          d[jj] = (u32)f2bf(lo) | ((u32)f2bf(hi) << 16);
        }
        int win = bb * 144 + (y >> 4) * 12 + (px >> 4);
        int sp  = (y & 15) * 16 + (px & 15);
        b16* dst = xw + (long)inp * XN + (long)win * WELEM + sp * CCH + grp * 32 + k * 8;
        uint4 q;
        q.x = d[0]; q.y = d[1]; q.z = d[2]; q.w = d[3];
        *reinterpret_cast<uint4*>(dst) = q;  // 4 lanes -> one full 64B line
      }
    }
    // ---- all waves done reading buffer i&1 before it is re-targeted
    __builtin_amdgcn_sched_barrier(0);
    __builtin_amdgcn_s_barrier();
  }
}

// ---------------------------------------------------------------------------
// Shared bt-GEMM core: D[256 m][128 n] = A[256][256] * Bt[128][256]^T
// ---------------------------------------------------------------------------
DEVI void btgemm_core(const b16* __restrict__ Aw, const b16* __restrict__ Bt,
                      b16* as_, b16* bs_, int lane, int wid, f32x4 (&acc)[4][4])
{
  int wm = wid >> 1, wn = wid & 1, quad = lane >> 4, l15 = lane & 15;
  for (int kc = 0; kc < 4; kc++) {
    int c0 = kc * 64;
    __syncthreads();
#pragma unroll
    for (int i = 0; i < 4; i++) {          // stage A: 256 rows x 64 c
      int it  = wid * 4 + i;
      int row = it * 8 + (lane >> 3);
      int g   = (lane & 7) ^ (row & 7);    // slot lane&7 holds group g
      gl2lds16(Aw + row * CCH + c0 + g * 8, as_ + it * 512);
    }
#pragma unroll
    for (int i = 0; i < 2; i++) {          // stage Bt: 128 rows x 64 c
      int it  = wid * 2 + i;
      int row = it * 8 + (lane >> 3);
      int g   = (lane & 7) ^ (row & 7);
      gl2lds16(Bt + row * CCH + c0 + g * 8, bs_ + it * 512);
    }
    __syncthreads();
#pragma unroll
    for (int kk = 0; kk < 2; kk++) {
      short8 af[4], bfv[4];
#pragma unroll
      for (int mt = 0; mt < 4; mt++) {
        int row = wm * 64 + mt * 16 + l15;
        int g   = (kk * 4 + quad) ^ (row & 7);
        af[mt]  = lds8(as_ + row * 64 + g * 8);
      }
#pragma unroll
      for (int nt = 0; nt < 4; nt++) {
        int row = wn * 64 + nt * 16 + l15;
        int g   = (kk * 4 + quad) ^ (row & 7);
        bfv[nt] = lds8(bs_ + row * 64 + g * 8);
      }
#pragma unroll
      for (int mt = 0; mt < 4; mt++)
#pragma unroll
        for (int nt = 0; nt < 4; nt++)
          acc[mt][nt] = __builtin_amdgcn_mfma_f32_16x16x32_bf16(
              af[mt], bfv[nt], acc[mt][nt], 0, 0, 0);
    }
  }
}

// ---------------------------------------------------------------------------
// Kernel A: QKV projection. mode 0/1/2 = Q/K/V.
// Q,K -> [win][s][c] ; V -> transposed [win][c][s]
// Q is pre-scaled by (1/sqrt(32))*log2(e) so attn can exp2 scores directly.
// ---------------------------------------------------------------------------
__global__ __launch_bounds__(512) void qkv_kernel(
    const b16* __restrict__ xw, const b16* __restrict__ Wb,
    const float* __restrict__ bq, const float* __restrict__ bk,
    const float* __restrict__ bv,
    b16* __restrict__ QW, b16* __restrict__ KW, b16* __restrict__ VT)
{
  __shared__ b16 as_[256 * 64];
  __shared__ b16 bs_[128 * 64];
  int bid  = blockIdx.x;
  int mode = bid / 576;
  int rem  = bid % 576;
  int win  = rem >> 1;
  int sp0  = (rem & 1) * 128;
  const b16* Aw = Wb + mode * 65536;
  const b16* Bt = xw + (mode ? XN : 0) + (long)win * WELEM + sp0 * CCH;
  const float* bias = mode == 0 ? bq : mode == 1 ? bk : bv;
  int lane = threadIdx.x & 63, wid = threadIdx.x >> 6;
  int wm = wid >> 1, wn = wid & 1, quad = lane >> 4, l15 = lane & 15;

  f32x4 acc[4][4];
  const f32x4 ZV = {0.f, 0.f, 0.f, 0.f};
#pragma unroll
  for (int i = 0; i < 4; i++)
#pragma unroll
    for (int j = 0; j < 4; j++) acc[i][j] = ZV;

  btgemm_core(Aw, Bt, as_, bs_, lane, wid, acc);

  if (mode < 2) {
    float qs = (mode == 0) ? 0.25505392f : 1.0f;   // (1/sqrt(32))*log2(e)
    b16* Out = (mode == 0 ? QW : KW) + (long)win * WELEM;
#pragma unroll
    for (int mt = 0; mt < 4; mt++) {
      int d0 = wm * 64 + mt * 16 + quad * 4;
      f32x4 bb = *reinterpret_cast<const f32x4*>(bias + d0);
#pragma unroll
      for (int nt = 0; nt < 4; nt++) {
        int sp = sp0 + wn * 64 + nt * 16 + l15;
        uint2 pk;
        pk.x = f2bf((acc[mt][nt][0] + bb[0]) * qs) | ((u32)f2bf((acc[mt][nt][1] + bb[1]) * qs) << 16);
        pk.y = f2bf((acc[mt][nt][2] + bb[2]) * qs) | ((u32)f2bf((acc[mt][nt][3] + bb[3]) * qs) << 16);
        *reinterpret_cast<uint2*>(Out + (long)sp * CCH + d0) = pk;
      }
    }
  } else {
    b16* Out = VT + (long)win * WELEM;
#pragma unroll
    for (int mt = 0; mt < 4; mt++) {
      int d0 = wm * 64 + mt * 16 + quad * 4;
      f32x4 bb = *reinterpret_cast<const f32x4*>(bias + d0);
#pragma unroll
      for (int nt = 0; nt < 4; nt++) {
        int sp = sp0 + wn * 64 + nt * 16 + l15;
#pragma unroll
        for (int r = 0; r < 4; r++)
          Out[(long)(d0 + r) * WTOK + sp] = f2bf(acc[mt][nt][r] + bb[r]);
      }
    }
  }
}

// ---------------------------------------------------------------------------
// Kernel B: attention per (window, head). 4 waves, wave = 64 queries.
// Non-online softmax (S=256, scores O(1), exp2 overflow impossible):
//   P_hat = trunc-bf16(exp2(score')), O = (V^T P_hat^T), l = sum(P_hat),
//   out = O / l.  Sum uses the SAME truncated values as the MFMA.
// ---------------------------------------------------------------------------
__global__ __launch_bounds__(256) void attn_kernel(
    const b16* __restrict__ QW, const b16* __restrict__ KW,
    const b16* __restrict__ VT, b16* __restrict__ AW)
{
  __shared__ b16 ks[256 * 32];     // [key][d]  16 KB
  __shared__ b16 vs[32 * 256];     // [d][s] (16B-group XOR swizzled) 16 KB
  __shared__ b16 ps[4 * 64 * 40];  // per-wave P^T, rows 40 el  20 KB
  int bid = blockIdx.x;
  int win = bid >> 3, head = bid & 7;
  int lane = threadIdx.x & 63, wid = threadIdx.x >> 6;
  int quad = lane >> 4, l15 = lane & 15;

  const b16* Kg = KW + (long)win * WELEM + head * 32;
  const b16* Vg = VT + (long)win * WELEM + head * 32 * WTOK;
  const b16* Qg = QW + (long)win * WELEM + head * 32;

#pragma unroll
  for (int i = 0; i < 4; i++) {            // stage K slice: 256 x 32
    int it  = wid * 4 + i;
    int key = it * 16 + (lane >> 2);
    gl2lds16(Kg + key * CCH + (lane & 3) * 8, ks + it * 512);
  }
#pragma unroll
  for (int i = 0; i < 4; i++) {            // stage V^T slice: 32 x 256, swizzled
    int it   = wid * 4 + i;
    int slot = it * 64 + lane;
    int d    = slot >> 5;
    int gp   = slot & 31;                  // stored slot
    int g    = (gp & 24) | ((gp & 7) ^ (d & 7));  // logical 16B group
    gl2lds16(Vg + d * WTOK + g * 8, vs + it * 512);
  }

  short8 qf[4];                            // Q fragments stay in registers
#pragma unroll
  for (int qt = 0; qt < 4; qt++) {
    int q = wid * 64 + qt * 16 + l15;
    qf[qt] = *reinterpret_cast<const short8*>(Qg + (long)q * CCH + quad * 8);
  }

  __syncthreads();

  const f32x4 ZV = {0.f, 0.f, 0.f, 0.f};
  f32x4 oacc[2][4];
#pragma unroll
  for (int mt = 0; mt < 2; mt++)
#pragma unroll
    for (int qt = 0; qt < 4; qt++) oacc[mt][qt] = ZV;
  float psum[4];
#pragma unroll
  for (int qt = 0; qt < 4; qt++) psum[qt] = 0.f;

  b16* psw = ps + wid * (64 * 40);

  for (int kb = 0; kb < 8; kb++) {         // 32 keys per iteration
    int k0 = kb * 32;
    short8 kf[2];
#pragma unroll
    for (int km = 0; km < 2; km++)
      kf[km] = lds8(ks + (k0 + km * 16 + l15) * 32 + quad * 8);
    f32x4 sc[2][4];                        // scores^T[key][q], pre-scaled
#pragma unroll
    for (int km = 0; km < 2; km++)
#pragma unroll
      for (int qt = 0; qt < 4; qt++)
        sc[km][qt] = __builtin_amdgcn_mfma_f32_16x16x32_bf16(kf[km], qf[qt], ZV, 0, 0, 0);

#pragma unroll
    for (int qt = 0; qt < 4; qt++) {
      int qrow = qt * 16 + l15;
#pragma unroll
      for (int km = 0; km < 2; km++) {
        u32 u0 = __float_as_uint(__builtin_amdgcn_exp2f(sc[km][qt][0])) & 0xffff0000u;
        u32 u1 = __float_as_uint(__builtin_amdgcn_exp2f(sc[km][qt][1])) & 0xffff0000u;
        u32 u2 = __float_as_uint(__builtin_amdgcn_exp2f(sc[km][qt][2])) & 0xffff0000u;
        u32 u3 = __float_as_uint(__builtin_amdgcn_exp2f(sc[km][qt][3])) & 0xffff0000u;
        psum[qt] += (__uint_as_float(u0) + __uint_as_float(u1))
                  + (__uint_as_float(u2) + __uint_as_float(u3));
        uint2 pk;
        pk.x = (u0 >> 16) | u1;
        pk.y = (u2 >> 16) | u3;
        *reinterpret_cast<uint2*>(psw + qrow * 40 + km * 16 + quad * 4) = pk;
      }
    }
    short8 vf[2], pf[4];
#pragma unroll
    for (int mt = 0; mt < 2; mt++) {       // V^T fragments (de-swizzle)
      int d  = mt * 16 + l15;
      int gl = kb * 4 + quad;
      int gs = (gl & 24) | ((gl & 7) ^ (d & 7));
      vf[mt] = lds8(vs + d * WTOK + gs * 8);
    }
#pragma unroll
    for (int qt = 0; qt < 4; qt++)
      pf[qt] = lds8(psw + (qt * 16 + l15) * 40 + quad * 8);
#pragma unroll
    for (int mt = 0; mt < 2; mt++)
#pragma unroll
      for (int qt = 0; qt < 4; qt++)
        oacc[mt][qt] = __builtin_amdgcn_mfma_f32_16x16x32_bf16(
            vf[mt], pf[qt], oacc[mt][qt], 0, 0, 0);
  }

  b16* Og = AW + (long)win * WELEM + head * 32;   // AW[win][s][c]
#pragma unroll
  for (int qt = 0; qt < 4; qt++) {
    float l = psum[qt];
    l += __shfl_xor(l, 16);
    l += __shfl_xor(l, 32);
    float rl = __builtin_amdgcn_rcpf(l);
    int q = wid * 64 + qt * 16 + l15;
#pragma unroll
    for (int mt = 0; mt < 2; mt++) {
      uint2 pk;
      pk.x = f2bf(oacc[mt][qt][0] * rl) | ((u32)f2bf(oacc[mt][qt][1] * rl) << 16);
      pk.y = f2bf(oacc[mt][qt][2] * rl) | ((u32)f2bf(oacc[mt][qt][3] * rl) << 16);
      *reinterpret_cast<uint2*>(Og + (long)q * CCH + mt * 16 + quad * 4) = pk;
    }
  }
}

// ---------------------------------------------------------------------------
// Kernel C: output projection, D[d][sp] -> natural (B,C,H,W) fp32 + bias
// ---------------------------------------------------------------------------
__global__ __launch_bounds__(512) void oproj_kernel(
    const b16* __restrict__ AW, const b16* __restrict__ Wb,
    const float* __restrict__ bo, float* __restrict__ out)
{
  __shared__ b16 as_[256 * 64];
  __shared__ b16 bs_[128 * 64];
  int bid = blockIdx.x;
  int win = bid >> 1;
  int sp0 = (bid & 1) * 128;
  const b16* Aw = Wb + 3 * 65536;
  const b16* Bt = AW + (long)win * WELEM + sp0 * CCH;
  int lane = threadIdx.x & 63, wid = threadIdx.x >> 6;
  int wm = wid >> 1, wn = wid & 1, quad = lane >> 4, l15 = lane & 15;

  f32x4 acc[4][4];
  const f32x4 ZV = {0.f, 0.f, 0.f, 0.f};
#pragma unroll
  for (int i = 0; i < 4; i++)
#pragma unroll
    for (int j = 0; j < 4; j++) acc[i][j] = ZV;

  btgemm_core(Aw, Bt, as_, bs_, lane, wid, acc);

  int b = win / 144, wh = (win / 12) % 12, ww = win % 12;
#pragma unroll
  for (int mt = 0; mt < 4; mt++) {
    int d0 = wm * 64 + mt * 16 + quad * 4;
    f32x4 bb = *reinterpret_cast<const f32x4*>(bo + d0);
#pragma unroll
    for (int nt = 0; nt < 4; nt++) {
      int sp = sp0 + wn * 64 + nt * 16 + l15;
      int y = sp >> 4, x = sp & 15;
      float* op = out + (long)b * CCH * PLANE + (long)(wh * 16 + y) * IMG + ww * 16 + x;
#pragma unroll
      for (int r = 0; r < 4; r++)
        op[(long)(d0 + r) * PLANE] = acc[mt][nt][r] + bb[r];
    }
  }
}

// ---------------------------------------------------------------------------
extern "C" void kernel_launch(void* const* d_in, const int* in_sizes, int n_in,
                              void* d_out, int out_size, void* d_ws, size_t ws_size,
                              hipStream_t stream)
{
  const float* xq  = (const float*)d_in[0];
  const float* xkv = (const float*)d_in[1];
  const float* Wq  = (const float*)d_in[2];
  const float* bq  = (const float*)d_in[3];
  const float* Wk  = (const float*)d_in[4];
  const float* bk  = (const float*)d_in[5];
  const float* Wv  = (const float*)d_in[6];
  const float* bv  = (const float*)d_in[7];
  const float* Wo  = (const float*)d_in[8];
  const float* bo  = (const float*)d_in[9];

  // workspace layout (bytes): needs ~189.3 MB
  char* ws = (char*)d_ws;
  b16* xw = (b16*)ws;                       // 2 * 18874368 * 2 = 75,497,472
  b16* QW = (b16*)(ws + 75497472);          // 37,748,736
  b16* KW = (b16*)(ws + 113246208);         // 37,748,736
  b16* VT = (b16*)(ws + 150994944);         // 37,748,736
  b16* Wb = (b16*)(ws + 188743680);         // 524,288
  b16* AW = xw;                             // alias: xw dead after qkv_kernel
  float* out = (float*)d_out;

  wprep_kernel<<<dim3(128), dim3(256), 0, stream>>>(Wq, Wk, Wv, Wo, Wb);
  prep_kernel<<<dim3(PREP_NB), dim3(256), 0, stream>>>(xq, xkv, xw);
  qkv_kernel<<<dim3(1728), dim3(512), 0, stream>>>(xw, Wb, bq, bk, bv, QW, KW, VT);
  attn_kernel<<<dim3(2304), dim3(256), 0, stream>>>(QW, KW, VT, AW);
  oproj_kernel<<<dim3(576), dim3(512), 0, stream>>>(AW, Wb, bo, out);
}